// Round 9
// baseline (184.150 us; speedup 1.0000x reference)
//
#include <hip/hip_runtime.h>
#include <math.h>

// IDMForwardSim R9: R8 + transposed GEMM (z^T = Wh^T.[h;sdv]^T). Same frag buffers,
// same ds_read_b128 (A/B layout transpose symmetry) — only MFMA operand order swaps.
// C-rows = j => packed ds_write_b64 h-writes (4 consecutive j per lane). Trans-diet
// gates (5 ex2 + 3 rcp/elem, fused sigma*tanh). sdv staging on wave-6 dead lanes.
// 512 blocks x 448 thr, 2 blocks/CU (VGPR-capped residency ceiling), 1 barrier/step.

#define B_TOT 8192
#define T_STEPS 40
#define NB 16

typedef _Float16 f16;
typedef f16 f16x4 __attribute__((ext_vector_type(4)));
typedef f16 f16x8 __attribute__((ext_vector_type(8)));
typedef float f32x4 __attribute__((ext_vector_type(4)));

__device__ __forceinline__ float rcpf(float x) { return __builtin_amdgcn_rcpf(x); }
__device__ __forceinline__ float ex2(float x)  { return __builtin_amdgcn_exp2f(x); }
__device__ __forceinline__ float sigf(float x)  { return rcpf(1.f + ex2(-1.44269504f * x)); }

// ws layout (bytes): whb f16[65536] @0 | wxb f16[65536] @131072 | bp f32[512] @262144

__global__ __launch_bounds__(256) void idm_prep(
    const float* __restrict__ Wx, const float* __restrict__ Wh,
    const float* __restrict__ bvec, const float* __restrict__ attw,
    f16* __restrict__ whb, f16* __restrict__ wxb,
    float* __restrict__ bp)
{
  int i = blockIdx.x * 256 + threadIdx.x;  // 0..65535, i = k*512 + n (coalesced reads)
  int k = i >> 9, n = i & 511;
  int g = n >> 7, j128 = n & 127;
  float vh = 0.f, vx = 0.f;
  if (j128 < 100) {
    int col = g * 100 + j128;
    if (k < 100)      { vh = Wh[k * 400 + col]; vx = Wx[k * 400 + col]; }
    else if (k < 102) { vh = Wx[k * 400 + col]; }  // sdv rows folded into Wh-pad
  } else if (n == 100 && k < 100) {
    vh = attw[k];  // logit row: z^T[100] = h . att_W
  }
  // frag index (serves as B-frag of W, equivalently A-frag of W^T):
  // tile=n>>4, kf=k>>5, l=((k>>3)&3)*16+(n&15), j=k&7
  int idx = (((n >> 4) * 4 + (k >> 5)) * 64 + (((k >> 3) & 3) * 16 + (n & 15))) * 8 + (k & 7);
  whb[idx] = (f16)vh;
  wxb[idx] = (f16)vx;
  if (i < 512) { int gg = i >> 7, jj = i & 127; bp[i] = (jj < 100) ? bvec[gg * 100 + jj] : 0.f; }
}

__global__ __launch_bounds__(448, 4) void idm_main(
    const float* __restrict__ z_att,
    const float* __restrict__ linear_W,
    const float* __restrict__ linear_b,
    const float* __restrict__ sdv_acts,
    const f16* __restrict__ whb, const f16* __restrict__ wxb,
    const float* __restrict__ bp,
    const float* __restrict__ idm_params,
    const float* __restrict__ idm_s,
    const float* __restrict__ att_b,
    const float* __restrict__ noise_f,
    const float* __restrict__ noise_m,
    float* __restrict__ out)
{
  __shared__ f16   hS[2][16][136];       // [buf][batch][k] 0..99 h, 100..101 sdv, pad 0
  __shared__ f16   sdvS[T_STEPS][16][2];
  __shared__ float logitS[T_STEPS][16];
  __shared__ float sS[16][T_STEPS][6];   // idm_s fields 1,2,4,5,6,7
  __shared__ float nS[2][T_STEPS][16];   // noise_f / noise_m
  __shared__ float accS[2][16][T_STEPS]; // act, att

  const int tid = threadIdx.x;
  const int w  = tid >> 6;   // 0..6 j-tile group
  const int l  = tid & 63;
  const int lr = l & 15;     // batch (C-col in transposed GEMM)
  const int lq = l >> 4;
  const int b0g = blockIdx.x * NB;
  const int j0 = 16 * w + lq * 4;   // this lane's 4 consecutive j: j0..j0+3

  // zero hS (pad rows must stay exact 0)
  for (int idx = tid; idx < 2176; idx += 448) ((unsigned*)hS)[idx] = 0u;
  // coalesced staging: sdv (1280 f), idm_s fields (5120 f), noise (1280 f)
  for (int idx = tid; idx < 1280; idx += 448) {
    float v = sdv_acts[(size_t)b0g * 80 + idx];
    int b = idx / 80, r = idx - b * 80;
    sdvS[r >> 1][b][r & 1] = (f16)v;
  }
  for (int idx = tid; idx < 5120; idx += 448) {
    int f = idx & 7;
    if (f != 0 && f != 3) {
      int b = idx / 320, rem = idx - b * 320, t = rem >> 3;
      sS[b][t][(f < 3) ? f - 1 : f - 2] = idm_s[(size_t)b0g * 320 + idx];
    }
  }
  for (int idx = tid; idx < 1280; idx += 448) {
    int which = idx >= 640 ? 1 : 0;
    int r = idx - which * 640;
    int t = r >> 4, i = r & 15;
    nS[which][t][i] = which ? noise_m[(size_t)t * B_TOT + b0g + i]
                            : noise_f[(size_t)t * B_TOT + b0g + i];
  }
  __syncthreads();

  // h0 = att_proj into hS[0]
  if (tid < 256) {
    int b = tid >> 4, oct = tid & 15;
    float za[10];
    #pragma unroll
    for (int t2 = 0; t2 < 10; ++t2) za[t2] = z_att[(b0g + b) * 10 + t2];
    #pragma unroll
    for (int jj = 0; jj < 8; ++jj) {
      int j = oct * 8 + jj;
      if (j < 100) {
        float acc = linear_b[j];
        #pragma unroll
        for (int t2 = 0; t2 < 10; ++t2) acc = fmaf(za[t2], linear_W[t2 * 100 + j], acc);
        hS[0][b][j] = (f16)acc;
      }
    }
  }
  if (tid < 32) hS[0][tid >> 1][100 + (tid & 1)] = sdvS[0][tid >> 1][tid & 1];
  __syncthreads();

  // Wx frags -> cx (transposed: mfma(W, h, c)), then Wh frags (loop-invariant in regs)
  f16x8 wb[4][4];
  #pragma unroll
  for (int g = 0; g < 4; ++g) {
    int tile = w + 8 * g;
    #pragma unroll
    for (int kf = 0; kf < 4; ++kf)
      wb[g][kf] = *(const f16x8*)(wxb + ((size_t)(tile * 4 + kf) * 64 + l) * 8);
  }
  f32x4 cx[4];
  #pragma unroll
  for (int g = 0; g < 4; ++g)
    cx[g] = *(const f32x4*)(bp + (w + 8 * g) * 16 + lq * 4);  // bias per j-row
  #pragma unroll
  for (int kf = 0; kf < 4; ++kf) {
    f16x8 a = *(const f16x8*)(&hS[0][lr][kf * 32 + lq * 8]);  // h B-frag (same bytes)
    #pragma unroll
    for (int g = 0; g < 4; ++g)
      cx[g] = __builtin_amdgcn_mfma_f32_16x16x32_f16(wb[g][kf], a, cx[g], 0, 0, 0);
  }
  #pragma unroll
  for (int g = 0; g < 4; ++g) {
    int tile = w + 8 * g;
    #pragma unroll
    for (int kf = 0; kf < 4; ++kf)
      wb[g][kf] = *(const f16x8*)(whb + ((size_t)(tile * 4 + kf) * 64 + l) * 8);
  }

  // c-state: 4 consecutive j (j0..j0+3) at batch lr
  float cst[4];
  #pragma unroll
  for (int r = 0; r < 4; ++r) cst[r] = (float)hS[0][lr][j0 + r];

  const bool hlive = (j0 < 100);                    // j0..j0+3 all <100 (j0 mult of 4)
  const bool sduty = (w == 6) && (lq == 1 || lq == 2);  // dead-lane sdv stagers
  const int sb = (lq - 1) * 16 + lr;                // 0..31 for sduty lanes

  int p = 0;
  for (int t = 0; t < T_STEPS; ++t) {
    // B-frags for [h^{(t)}, sdv_t]
    f16x8 a0 = *(const f16x8*)(&hS[p][lr][0  + lq * 8]);
    f16x8 a1 = *(const f16x8*)(&hS[p][lr][32 + lq * 8]);
    f16x8 a2 = *(const f16x8*)(&hS[p][lr][64 + lq * 8]);
    f16x8 a3 = *(const f16x8*)(&hS[p][lr][96 + lq * 8]);
    f32x4 z0 = cx[0], z1 = cx[1], z2 = cx[2], z3 = cx[3];
    z0 = __builtin_amdgcn_mfma_f32_16x16x32_f16(wb[0][0], a0, z0, 0, 0, 0);
    z1 = __builtin_amdgcn_mfma_f32_16x16x32_f16(wb[1][0], a0, z1, 0, 0, 0);
    z2 = __builtin_amdgcn_mfma_f32_16x16x32_f16(wb[2][0], a0, z2, 0, 0, 0);
    z3 = __builtin_amdgcn_mfma_f32_16x16x32_f16(wb[3][0], a0, z3, 0, 0, 0);
    z0 = __builtin_amdgcn_mfma_f32_16x16x32_f16(wb[0][1], a1, z0, 0, 0, 0);
    z1 = __builtin_amdgcn_mfma_f32_16x16x32_f16(wb[1][1], a1, z1, 0, 0, 0);
    z2 = __builtin_amdgcn_mfma_f32_16x16x32_f16(wb[2][1], a1, z2, 0, 0, 0);
    z3 = __builtin_amdgcn_mfma_f32_16x16x32_f16(wb[3][1], a1, z3, 0, 0, 0);
    z0 = __builtin_amdgcn_mfma_f32_16x16x32_f16(wb[0][2], a2, z0, 0, 0, 0);
    z1 = __builtin_amdgcn_mfma_f32_16x16x32_f16(wb[1][2], a2, z1, 0, 0, 0);
    z2 = __builtin_amdgcn_mfma_f32_16x16x32_f16(wb[2][2], a2, z2, 0, 0, 0);
    z3 = __builtin_amdgcn_mfma_f32_16x16x32_f16(wb[3][2], a2, z3, 0, 0, 0);
    z0 = __builtin_amdgcn_mfma_f32_16x16x32_f16(wb[0][3], a3, z0, 0, 0, 0);
    z1 = __builtin_amdgcn_mfma_f32_16x16x32_f16(wb[1][3], a3, z1, 0, 0, 0);
    z2 = __builtin_amdgcn_mfma_f32_16x16x32_f16(wb[2][3], a3, z2, 0, 0, 0);
    z3 = __builtin_amdgcn_mfma_f32_16x16x32_f16(wb[3][3], a3, z3, 0, 0, 0);

    // logit for output t-1: z row 100 (tile 6, row-in-tile 4 -> lq==1, reg 0), col=batch
    if (w == 6 && lq == 1 && t > 0) logitS[t - 1][lr] = z0[0];

    // gates: 4 (batch=lr, j=j0+r); fused sigma*tanh (5 ex2 + 3 rcp per elem)
    f16x4 h4;
    #pragma unroll
    for (int r = 0; r < 4; ++r) {
      float ei = ex2(-1.44269504f * z0[r]);
      float sf = sigf(z1[r]);
      float eg = ex2(-2.88539008f * fmaxf(z2[r], -30.f));
      float it = (1.f - eg) * rcpf((1.f + ei) * (1.f + eg));
      float cc = fmaf(sf, cst[r], it);
      float eo = ex2(-1.44269504f * z3[r]);
      float ec = ex2(-2.88539008f * fmaxf(cc, -30.f));
      float hh = (1.f - ec) * rcpf((1.f + eo) * (1.f + ec));
      cst[r] = cc;
      h4[r] = (f16)hh;
    }
    if (hlive) *(f16x4*)(&hS[p ^ 1][lr][j0]) = h4;  // one packed b64 write
    if (sduty && t + 1 < T_STEPS)
      hS[p ^ 1][sb >> 1][100 + (sb & 1)] = sdvS[t + 1][sb >> 1][sb & 1];
    __syncthreads();  // single barrier per step
    p ^= 1;
  }

  // final logit (t = T-1) from h^{(T)} in hS[p]: 4 MFMA on tile 6
  if (w == 6) {
    f32x4 zL = {0.f, 0.f, 0.f, 0.f};
    #pragma unroll
    for (int kf = 0; kf < 4; ++kf) {
      f16x8 a = *(const f16x8*)(&hS[p][lr][kf * 32 + lq * 8]);
      zL = __builtin_amdgcn_mfma_f32_16x16x32_f16(wb[0][kf], a, zL, 0, 0, 0);
    }
    if (lq == 1) logitS[T_STEPS - 1][lr] = zL[0];
  }
  __syncthreads();

  // ---- tail: per-batch ego/IDM chain, all per-step operands in LDS ----
  if (tid < 16) {
    int b = b0g + tid;
    const float* P = idm_params + (size_t)b * 5;
    float des_v = P[0], des_tg = P[1], min_jx = P[2], max_a = P[3];
    float inv2s = 0.5f / sqrtf(max_a * P[4]);
    float inv_dv = rcpf(des_v);
    float ego_v = idm_s[(size_t)b * 320 + 0];
    float ego_x = idm_s[(size_t)b * 320 + 3];
    float attb = att_b[0];
    float act = 0.f;
    #pragma unroll 4
    for (int t = 0; t < T_STEPS; ++t) {
      float2 s01 = *(const float2*)&sS[tid][t][0];  // f_v, m_v
      float2 s23 = *(const float2*)&sS[tid][t][2];  // f_x, m_x
      float2 s45 = *(const float2*)&sS[tid][t][4];  // f_ex, m_ex
      float nf = nS[0][t][tid], nm = nS[1][t][tid];
      float lg = attb + logitS[t][tid];
      ego_v += act * 0.1f;
      ego_x += ego_v * 0.1f + act * 0.005f;
      float af_, am_;
      {
        float dx = fminf(fmaxf(s23.x - ego_x, 0.5f), 1000.f);
        float dg = min_jx + fmaxf(0.f, des_tg * ego_v + ego_v * (ego_v - s01.x) * inv2s);
        float r = ego_v * inv_dv; float r2 = r * r; float q = dg * rcpf(dx);
        af_ = fminf(fmaxf(max_a * (1.f - r2 * r2 - q * q), -3.f), 3.f);
      }
      {
        float dx = fminf(fmaxf(s23.y - ego_x, 0.5f), 1000.f);
        float dg = min_jx + fmaxf(0.f, des_tg * ego_v + ego_v * (ego_v - s01.y) * inv2s);
        float r = ego_v * inv_dv; float r2 = r * r; float q = dg * rcpf(dx);
        am_ = fminf(fmaxf(max_a * (1.f - r2 * r2 - q * q), -3.f), 3.f);
      }
      float ef2 = s45.x * af_ + (1.f - s45.x) * nf;
      float em2 = s45.y * am_ + (1.f - s45.y) * nm;
      float att = sigf(5.f * lg);
      act = (1.f - att) * ef2 + att * em2;
      accS[0][tid][t] = act;
      accS[1][tid][t] = att;
    }
  }
  __syncthreads();

  // coalesced output store: 640 floats per output
  if (tid < 160) {
    f32x4 va = ((const f32x4*)&accS[0][0][0])[tid];
    f32x4 vt = ((const f32x4*)&accS[1][0][0])[tid];
    *(f32x4*)(out + (size_t)b0g * T_STEPS + tid * 4) = va;
    *(f32x4*)(out + (size_t)B_TOT * T_STEPS + (size_t)b0g * T_STEPS + tid * 4) = vt;
  }
}

extern "C" void kernel_launch(void* const* d_in, const int* in_sizes, int n_in,
                              void* d_out, int out_size, void* d_ws, size_t ws_size,
                              hipStream_t stream) {
  const float* z_att      = (const float*)d_in[0];
  const float* idm_params = (const float*)d_in[2];
  const float* idm_s      = (const float*)d_in[3];
  const float* sdv_acts   = (const float*)d_in[4];
  const float* linear_W   = (const float*)d_in[5];
  const float* linear_b   = (const float*)d_in[6];
  const float* lstm_Wx    = (const float*)d_in[7];
  const float* lstm_Wh    = (const float*)d_in[8];
  const float* lstm_b     = (const float*)d_in[9];
  const float* att_W      = (const float*)d_in[10];
  const float* att_b      = (const float*)d_in[11];
  const float* noise_f    = (const float*)d_in[12];
  const float* noise_m    = (const float*)d_in[13];
  float* out = (float*)d_out;

  f16*   whb = (f16*)d_ws;
  f16*   wxb = (f16*)((char*)d_ws + 131072);
  float* bp  = (float*)((char*)d_ws + 262144);

  idm_prep<<<256, 256, 0, stream>>>(lstm_Wx, lstm_Wh, lstm_b, att_W, whb, wxb, bp);
  idm_main<<<B_TOT / NB, 448, 0, stream>>>(z_att, linear_W, linear_b, sdv_acts,
                                           whb, wxb, bp,
                                           idm_params, idm_s, att_b,
                                           noise_f, noise_m, out);
}